// Round 16
// baseline (12642.691 us; speedup 1.0000x reference)
//
#include <hip/hip_runtime.h>
#include <math.h>

#define H    1024
#define H3   3072
#define DIN  512
#define VSZ  32000
#define SS   64
#define BB   128
#define TP   47
#define NROWS (TP*BB)      // 6016
#define VCHUNKS 250        // 32000 / 128
#define FMARGIN 0.1f
#define NBLK 256
#define HS   65536         // u32 per packed state step (128*1024/2)
#define CTXPL_S 62         // ctxp rows pinned in LDS (s=62,63 from global)

typedef unsigned short u16;
typedef unsigned int u32;
typedef unsigned long long u64;
typedef __bf16 bf16_t;
typedef bf16_t bf16x8 __attribute__((ext_vector_type(8)));
typedef float f32x4 __attribute__((ext_vector_type(4)));
typedef u16 u16x4 __attribute__((ext_vector_type(4)));
typedef u16 u16x8 __attribute__((ext_vector_type(8)));

#define MFMA __builtin_amdgcn_mfma_f32_16x16x32_bf16

__device__ inline u16 f2bf(float f){
    unsigned b = __float_as_uint(f);
    return (u16)((b + 0x7FFFu + ((b >> 16) & 1u)) >> 16);
}
__device__ inline float bf2f(u16 u){ return __uint_as_float(((unsigned)u) << 16); }
__device__ inline float sigm(float x){ return 1.f/(1.f + expf(-x)); }

__device__ inline void stoval(float* p, float v){ *p = v; }
__device__ inline void stoval(u16* p, float v){ *p = f2bf(v); }

__device__ inline void cstore(u32* p, u32 v){ __hip_atomic_store(p, v, __ATOMIC_RELAXED, __HIP_MEMORY_SCOPE_AGENT); }
__device__ inline void cstoref(float* p, float v){ __hip_atomic_store(p, v, __ATOMIC_RELAXED, __HIP_MEMORY_SCOPE_AGENT); }
__device__ inline void cstore64(u64* p, u64 v){ __hip_atomic_store(p, v, __ATOMIC_RELAXED, __HIP_MEMORY_SCOPE_AGENT); }
__device__ inline float cloadf(const float* p){ return __hip_atomic_load(p, __ATOMIC_RELAXED, __HIP_MEMORY_SCOPE_AGENT); }

// producer-counter sync (monotone generations; no resets -> race-free)
// producer: all block work done -> +1 (RELEASE); consumer: poll >= tgt (ACQUIRE)
__device__ inline void cprod(u32* c, int tid){
    __syncthreads();                      // drains each wave's outstanding stores
    if (tid == 0){
        __builtin_amdgcn_s_waitcnt(0);
        __hip_atomic_fetch_add(c, 1u, __ATOMIC_RELEASE, __HIP_MEMORY_SCOPE_AGENT);
    }
}
__device__ inline void cwait(u32* c, u32 tgt, int tid){
    if (tid == 0){
        while (__hip_atomic_load(c, __ATOMIC_ACQUIRE, __HIP_MEMORY_SCOPE_AGENT) < tgt)
            __builtin_amdgcn_s_sleep(1);
    }
    __syncthreads();
    asm volatile("" ::: "memory");
}

// ---------- init helpers ----------

__global__ __launch_bounds__(128) void k_mask_sum(const float* __restrict__ mask, float* __restrict__ msum){
    int b = threadIdx.x;
    if (b < BB){ float s = 0.f; for (int i = 0; i < SS; i++) s += mask[i*BB + b]; msum[b] = s; }
}

__global__ __launch_bounds__(256) void k_mean_ctx(const float* __restrict__ ctx, const float* __restrict__ msum,
                                                  float* __restrict__ mean){
    int idx = blockIdx.x*256 + threadIdx.x;
    if (idx < BB*H){
        float s = 0.f;
        for (int i = 0; i < SS; i++) s += ctx[(size_t)i*BB*H + idx];
        mean[idx] = s / msum[idx / H];
    }
}

__global__ __launch_bounds__(256) void k_f32bf(const float* __restrict__ in, u16* __restrict__ out, int n4){
    int i = blockIdx.x*256 + threadIdx.x;
    if (i >= n4) return;
    float4 v = ((const float4*)in)[i];
    u16x4 o = { f2bf(v.x), f2bf(v.y), f2bf(v.z), f2bf(v.w) };
    ((u16x4*)out)[i] = o;
}

__global__ __launch_bounds__(256) void k_pack_h0(const float* __restrict__ h0, u32* __restrict__ hsHI,
                                                 u32* __restrict__ hsLO){
    int i = blockIdx.x*256 + threadIdx.x;    // < 65536
    float v0 = h0[i*2], v1 = h0[i*2 + 1];
    u16 a = f2bf(v0), b = f2bf(v1);
    hsHI[i] = (u32)a | ((u32)b << 16);
    hsLO[i] = (u32)f2bf(v0 - bf2f(a)) | ((u32)f2bf(v1 - bf2f(b)) << 16);
}

__global__ __launch_bounds__(256) void k_f2bf_frag(const float* __restrict__ in, u16* __restrict__ out,
                                                   int RK8, int K8){
    int t = blockIdx.x*256 + threadIdx.x;
    if (t >= RK8) return;
    int r = t / K8, k8 = t - r*K8;
    const float* p = in + (size_t)r*K8*8 + k8*8;
    float4 a = *(const float4*)p;
    float4 b = *(const float4*)(p + 4);
    size_t dst = ((size_t)(r >> 4)*(K8 >> 2) + (k8 >> 2))*512 + (size_t)((r & 15) + (k8 & 3)*16)*8;
    u16x8 o;
    o[0]=f2bf(a.x); o[1]=f2bf(a.y); o[2]=f2bf(a.z); o[3]=f2bf(a.w);
    o[4]=f2bf(b.x); o[5]=f2bf(b.y); o[6]=f2bf(b.z); o[7]=f2bf(b.w);
    *(u16x8*)(out + dst) = o;
}

__global__ __launch_bounds__(256) void k_rownorm_frag(const float* __restrict__ in, u16* __restrict__ out,
                                                      int nrows){
    int w = threadIdx.x >> 6, lane = threadIdx.x & 63;
    int row = blockIdx.x*4 + w;
    if (row >= nrows) return;
    const float* r = in + (size_t)row*512 + lane*8;
    float4 a = *(const float4*)r;
    float4 b = *(const float4*)(r + 4);
    float s = a.x*a.x + a.y*a.y + a.z*a.z + a.w*a.w
            + b.x*b.x + b.y*b.y + b.z*b.z + b.w*b.w;
    #pragma unroll
    for (int off = 32; off; off >>= 1) s += __shfl_xor(s, off);
    float inv = rsqrtf(s);
    size_t dst = ((size_t)(row >> 4)*16 + (lane >> 2))*512 + (size_t)((row & 15) + (lane & 3)*16)*8;
    u16x8 o;
    o[0]=f2bf(a.x*inv); o[1]=f2bf(a.y*inv); o[2]=f2bf(a.z*inv); o[3]=f2bf(a.w*inv);
    o[4]=f2bf(b.x*inv); o[5]=f2bf(b.y*inv); o[6]=f2bf(b.z*inv); o[7]=f2bf(b.w*inv);
    *(u16x8*)(out + dst) = o;
}

__global__ __launch_bounds__(256) void k_emb_frag(const float* __restrict__ emb, const int* __restrict__ y,
                                                  u16* __restrict__ out){
    int w = threadIdx.x >> 6, lane = threadIdx.x & 63;
    int row = blockIdx.x*4 + w;            // < 6016
    int src = y[row];
    const float* r = emb + (size_t)src*512 + lane*8;
    float4 a = *(const float4*)r;
    float4 b = *(const float4*)(r + 4);
    size_t dst = ((size_t)(row >> 4)*16 + (lane >> 2))*512 + (size_t)((row & 15) + (lane & 3)*16)*8;
    u16x8 o;
    o[0]=f2bf(a.x); o[1]=f2bf(a.y); o[2]=f2bf(a.z); o[3]=f2bf(a.w);
    o[4]=f2bf(b.x); o[5]=f2bf(b.y); o[6]=f2bf(b.z); o[7]=f2bf(b.w);
    *(u16x8*)(out + dst) = o;
}

// ---------- fp32 GEMM (h0 init only) ----------
template<int ACT>
__global__ __launch_bounds__(256) void k_gemm_nt(const float* __restrict__ A, const float* __restrict__ W,
                                                 const float* __restrict__ bias, float* __restrict__ C,
                                                 int M, int N, int K){
    __shared__ float As[16][68];
    __shared__ float Ws[16][68];
    int tid = threadIdx.x;
    int bm = blockIdx.y*64, bn = blockIdx.x*64;
    int lr = tid >> 2;
    int lk = (tid & 3) * 4;
    int tr = (tid >> 4) * 4;
    int tc = (tid & 15) * 4;
    float acc[4][4] = {};
    const float* Abase = A + (size_t)(bm + lr)*K;
    const float* Wbase = W + (size_t)(bn + lr)*K;
    for (int k0 = 0; k0 < K; k0 += 16){
        float4 av = *(const float4*)(Abase + k0 + lk);
        float4 wv = *(const float4*)(Wbase + k0 + lk);
        __syncthreads();
        As[lk+0][lr]=av.x; As[lk+1][lr]=av.y; As[lk+2][lr]=av.z; As[lk+3][lr]=av.w;
        Ws[lk+0][lr]=wv.x; Ws[lk+1][lr]=wv.y; Ws[lk+2][lr]=wv.z; Ws[lk+3][lr]=wv.w;
        __syncthreads();
        #pragma unroll
        for (int kk = 0; kk < 16; kk++){
            float4 a = *(const float4*)&As[kk][tr];
            float4 w = *(const float4*)&Ws[kk][tc];
            acc[0][0] += a.x*w.x; acc[0][1] += a.x*w.y; acc[0][2] += a.x*w.z; acc[0][3] += a.x*w.w;
            acc[1][0] += a.y*w.x; acc[1][1] += a.y*w.y; acc[1][2] += a.y*w.z; acc[1][3] += a.y*w.w;
            acc[2][0] += a.z*w.x; acc[2][1] += a.z*w.y; acc[2][2] += a.z*w.z; acc[2][3] += a.z*w.w;
            acc[3][0] += a.w*w.x; acc[3][1] += a.w*w.y; acc[3][2] += a.w*w.z; acc[3][3] += a.w*w.w;
        }
    }
    #pragma unroll
    for (int i = 0; i < 4; i++){
        #pragma unroll
        for (int j = 0; j < 4; j++){
            float v = acc[i][j];
            if (bias) v += bias[bn + tc + j];
            if (ACT == 1) v = tanhf(v);
            C[(size_t)(bm + tr + i)*N + bn + tc + j] = v;
        }
    }
}

// ---------- batched bf16 MFMA GEMM ----------
template<int AFRAG, int ACT, typename OutT>
__global__ __launch_bounds__(256) void k_gemmf(const u16* __restrict__ A, const u16* __restrict__ B,
                                               const float* __restrict__ bias, OutT* __restrict__ C,
                                               int M, int N, int K){
    int tid = threadIdx.x, lane = tid & 63, w = tid >> 6;
    int wm = w >> 1, wn = w & 1;
    int row0 = blockIdx.y*128 + wm*64, col0 = blockIdx.x*128 + wn*64;
    int r16 = lane & 15, kg8 = (lane >> 4)*8, rg = (lane >> 4)*4;
    int K32 = K >> 5;
    f32x4 acc[4][4] = {};
    for (int k0 = 0; k0 < K32; k0++){
        bf16x8 af[4], bfv[4];
        #pragma unroll
        for (int i = 0; i < 4; i++){
            if (AFRAG) af[i] = *(const bf16x8*)(A + (((size_t)((row0 >> 4) + i)*K32 + k0) << 9) + lane*8);
            else       af[i] = *(const bf16x8*)(A + (size_t)(row0 + i*16 + r16)*K + k0*32 + kg8);
        }
        #pragma unroll
        for (int j = 0; j < 4; j++)
            bfv[j] = *(const bf16x8*)(B + (((size_t)((col0 >> 4) + j)*K32 + k0) << 9) + lane*8);
        #pragma unroll
        for (int i = 0; i < 4; i++)
            #pragma unroll
            for (int j = 0; j < 4; j++)
                acc[i][j] = MFMA(af[i], bfv[j], acc[i][j], 0, 0, 0);
    }
    #pragma unroll
    for (int i = 0; i < 4; i++){
        #pragma unroll
        for (int j = 0; j < 4; j++){
            #pragma unroll
            for (int r = 0; r < 4; r++){
                int row = row0 + i*16 + rg + r;
                int col = col0 + j*16 + r16;
                float v = acc[i][j][r];
                if (bias) v += bias[col];
                if (ACT) v = tanhf(v);
                stoval(C + (size_t)row*N + col, v);
            }
        }
    }
}

// ---------- persistent recurrence: producer-counter dataflow sync ----------
// counters: bar[0]=sA(h1,64) bar[32]=sB(proj,64) bar[64]=sC(zt+gh1,256) bar[96]=sD(hs,64)
struct RK {
    const u16 *gi0, *Whh0, *Wh2c, *Wih1, *Whh1, *ctxp;
    const float *bhh0, *bih1, *bhh1, *vatt, *mask, *ctxf;
    u32 *hsHI, *hsLO, *h1HI, *h1LO, *ztHI, *ztLO;
    float *prF;    // per-step (aliased on Woutf)
    float *ghF;    // single BB*H3 (WAR-safe: writes at t start after sA(t) >= sD(t-1) >= P4(t-1) reads)
    float *spar;   // per-step partial scores
    u32 *flg;      // pairwise flags
    u16 *h2all;
    u32 *bar;
};

__global__ __launch_bounds__(512) void k_recur10(RK a){
    __shared__ u16 wlds[49152];            // 96 KB weights
    __shared__ u16 ctxpL[CTXPL_S*512];     // 62 KB ctxp (b,half) slice
    __shared__ float sal[SS];
    const int tid = threadIdx.x, lane = tid & 63, wv = tid >> 6;
    const int bid = blockIdx.x;
    const int r16 = lane & 15, rg = (lane >> 4)*4, kq4 = (lane >> 4)*4;
    const int ab = (bid & 7)*16 + ((bid >> 3) >> 1);
    const int ahalf = (bid >> 3) & 1;
    u32* sA = a.bar + 0;
    u32* sB = a.bar + 32;
    u32* sC = a.bar + 64;
    u32* sD = a.bar + 96;

    {   // weight slices -> LDS
        auto cp32k = [&](const u16* gsrc, int tile, int base){
            const u32* s = (const u32*)(gsrc + (size_t)tile*16384);
            u32* d = (u32*)(wlds + base);
            #pragma unroll
            for (int i = 0; i < 16; i++) d[tid + i*512] = s[tid + i*512];
        };
        if (bid < 64){
            cp32k(a.Whh0, bid, 0); cp32k(a.Whh0, 64+bid, 16384); cp32k(a.Whh0, 128+bid, 32768);
        } else if (bid < 128){
            int jt = bid - 64;
            cp32k(a.Wih1, jt, 0); cp32k(a.Wih1, 64+jt, 16384); cp32k(a.Wih1, 128+jt, 32768);
        } else if (bid < 192){
            int wt = bid - 128;
            cp32k(a.Whh1, 3*wt, 0); cp32k(a.Whh1, 3*wt+1, 16384); cp32k(a.Whh1, 3*wt+2, 32768);
        } else {
            cp32k(a.Wh2c, bid-192, 0);
        }
        for (int i = tid; i < CTXPL_S*512/8; i += 512){
            int s = (i*8) >> 9, h = (i*8) & 511;
            *(u16x8*)(ctxpL + i*8) = *(const u16x8*)(a.ctxp + ((size_t)(s*BB + ab))*H + ahalf*512 + h);
        }
    }
    float vv[8];
    {
        float4 v0 = *(const float4*)(a.vatt + ahalf*512 + lane*8);
        float4 v1 = *(const float4*)(a.vatt + ahalf*512 + lane*8 + 4);
        vv[0]=v0.x; vv[1]=v0.y; vv[2]=v0.z; vv[3]=v0.w;
        vv[4]=v1.x; vv[5]=v1.y; vv[6]=v1.z; vv[7]=v1.w;
    }
    __syncthreads();

    // ---- phase bodies as lambdas ----
    auto P1 = [&](int t){
        const u32* AbH = a.hsHI + (size_t)t*HS + (size_t)(wv*16 + r16)*512 + kq4;
        const u32* AbL = a.hsLO + (size_t)t*HS + (size_t)(wv*16 + r16)*512 + kq4;
        f32x4 ac0 = {}, ac1 = {}, ac2 = {};
        for (int k0 = 0; k0 < 32; k0++){
            bf16x8 ah = *(const bf16x8*)(AbH + k0*16);
            bf16x8 al = *(const bf16x8*)(AbL + k0*16);
            bf16x8 b0 = *(const bf16x8*)(wlds + (k0*64 + lane)*8);
            bf16x8 b1 = *(const bf16x8*)(wlds + 16384 + (k0*64 + lane)*8);
            bf16x8 b2 = *(const bf16x8*)(wlds + 32768 + (k0*64 + lane)*8);
            ac0 = MFMA(ah, b0, ac0, 0, 0, 0); ac0 = MFMA(al, b0, ac0, 0, 0, 0);
            ac1 = MFMA(ah, b1, ac1, 0, 0, 0); ac1 = MFMA(al, b1, ac1, 0, 0, 0);
            ac2 = MFMA(ah, b2, ac2, 0, 0, 0); ac2 = MFMA(al, b2, ac2, 0, 0, 0);
        }
        const u16* gi = a.gi0 + (size_t)t*BB*H3;
        const u32* hsH = a.hsHI + (size_t)t*HS;
        const u32* hsL = a.hsLO + (size_t)t*HS;
        int sh = (r16 & 1)*16;
        #pragma unroll
        for (int r = 0; r < 4; r++){
            int b = wv*16 + rg + r, j = bid*16 + r16;
            float gr = bf2f(gi[(size_t)b*H3 + j]);
            float gz = bf2f(gi[(size_t)b*H3 + H + j]);
            float gn = bf2f(gi[(size_t)b*H3 + 2*H + j]);
            float hr = ac0[r] + a.bhh0[j];
            float hz = ac1[r] + a.bhh0[H + j];
            float hn = ac2[r] + a.bhh0[2*H + j];
            u32 uh = hsH[(size_t)b*512 + (j >> 1)];
            u32 ul = hsL[(size_t)b*512 + (j >> 1)];
            float hp = bf2f((u16)(uh >> sh)) + bf2f((u16)(ul >> sh));
            float rr = sigm(gr + hr), zz = sigm(gz + hz);
            float nn = tanhf(gn + rr*hn);
            float hv = (1.f - zz)*nn + zz*hp;
            u16 hib = f2bf(hv);
            u16 lob = f2bf(hv - bf2f(hib));
            u32 hip = (u32)__shfl_xor((int)(u32)hib, 1);
            u32 lop = (u32)__shfl_xor((int)(u32)lob, 1);
            if (!(r16 & 1)){
                cstore(a.h1HI + (size_t)t*HS + (size_t)b*512 + (j >> 1), (u32)hib | (hip << 16));
                cstore(a.h1LO + (size_t)t*HS + (size_t)b*512 + (j >> 1), (u32)lob | (lop << 16));
            }
        }
    };

    auto P2gh1 = [&](int t){
        const u32* AbH = a.h1HI + (size_t)t*HS + (size_t)(wv*16 + r16)*512 + kq4;
        const u32* AbL = a.h1LO + (size_t)t*HS + (size_t)(wv*16 + r16)*512 + kq4;
        int wt = bid - 128;
        f32x4 ac0 = {}, ac1 = {}, ac2 = {};
        for (int k0 = 0; k0 < 32; k0++){
            bf16x8 ah = *(const bf16x8*)(AbH + k0*16);
            bf16x8 al = *(const bf16x8*)(AbL + k0*16);
            bf16x8 b0 = *(const bf16x8*)(wlds + (k0*64 + lane)*8);
            bf16x8 b1 = *(const bf16x8*)(wlds + 16384 + (k0*64 + lane)*8);
            bf16x8 b2 = *(const bf16x8*)(wlds + 32768 + (k0*64 + lane)*8);
            ac0 = MFMA(ah, b0, ac0, 0, 0, 0); ac0 = MFMA(al, b0, ac0, 0, 0, 0);
            ac1 = MFMA(ah, b1, ac1, 0, 0, 0); ac1 = MFMA(al, b1, ac1, 0, 0, 0);
            ac2 = MFMA(ah, b2, ac2, 0, 0, 0); ac2 = MFMA(al, b2, ac2, 0, 0, 0);
        }
        #pragma unroll
        for (int r = 0; r < 4; r++){
            int b = wv*16 + rg + r;
            int c0 = wt*48 + r16;
            float p0 = __shfl_xor(ac0[r], 1);
            float p1 = __shfl_xor(ac1[r], 1);
            float p2 = __shfl_xor(ac2[r], 1);
            if (!(r16 & 1)){
                cstore64((u64*)(a.ghF + (size_t)b*H3 + c0),
                         (u64)__float_as_uint(ac0[r]) | ((u64)__float_as_uint(p0) << 32));
                cstore64((u64*)(a.ghF + (size_t)b*H3 + c0 + 16),
                         (u64)__float_as_uint(ac1[r]) | ((u64)__float_as_uint(p1) << 32));
                cstore64((u64*)(a.ghF + (size_t)b*H3 + c0 + 32),
                         (u64)__float_as_uint(ac2[r]) | ((u64)__float_as_uint(p2) << 32));
            }
        }
    };

    auto P2proj = [&](int t){
        float* prT = a.prF + (size_t)t*BB*H;
        const u32* AbH = a.h1HI + (size_t)t*HS + (size_t)(wv*16 + r16)*512 + kq4;
        const u32* AbL = a.h1LO + (size_t)t*HS + (size_t)(wv*16 + r16)*512 + kq4;
        f32x4 ac = {};
        for (int k0 = 0; k0 < 32; k0++){
            bf16x8 ah = *(const bf16x8*)(AbH + k0*16);
            bf16x8 al = *(const bf16x8*)(AbL + k0*16);
            bf16x8 bv = *(const bf16x8*)(wlds + (k0*64 + lane)*8);
            ac = MFMA(ah, bv, ac, 0, 0, 0); ac = MFMA(al, bv, ac, 0, 0, 0);
        }
        #pragma unroll
        for (int r = 0; r < 4; r++){
            int b = wv*16 + rg + r;
            int c0 = (bid - 192)*16 + r16;
            float p0 = __shfl_xor(ac[r], 1);
            if (!(r16 & 1))
                cstore64((u64*)(prT + (size_t)b*H + c0),
                         (u64)__float_as_uint(ac[r]) | ((u64)__float_as_uint(p0) << 32));
        }
    };

    auto P3 = [&](int t){
        float* prT = a.prF + (size_t)t*BB*H;
        float* spT = a.spar + (size_t)t*256*SS;
        float pj[8];
        {
            float4 q0 = *(const float4*)(prT + (size_t)ab*H + ahalf*512 + lane*8);
            float4 q1 = *(const float4*)(prT + (size_t)ab*H + ahalf*512 + lane*8 + 4);
            pj[0]=q0.x; pj[1]=q0.y; pj[2]=q0.z; pj[3]=q0.w;
            pj[4]=q1.x; pj[5]=q1.y; pj[6]=q1.z; pj[7]=q1.w;
        }
        #pragma unroll
        for (int q = 0; q < 8; q++){
            int s = wv*8 + q;
            u16x8 cv;
            if (s < CTXPL_S) cv = *(const u16x8*)(ctxpL + s*512 + lane*8);
            else cv = *(const u16x8*)(a.ctxp + ((size_t)(s*BB + ab))*H + ahalf*512 + lane*8);
            float acc = 0.f;
            #pragma unroll
            for (int e = 0; e < 8; e++) acc += tanhf(bf2f(cv[e]) + pj[e]) * vv[e];
            #pragma unroll
            for (int off = 32; off; off >>= 1) acc += __shfl_xor(acc, off);
            if (lane == 0) cstoref(spT + (ab*2 + ahalf)*SS + s, acc);
        }
        __syncthreads();
        if (tid == 0){
            __builtin_amdgcn_s_waitcnt(0);
            __hip_atomic_store(&a.flg[(ab*2 + ahalf)*32], (u32)(t+1), __ATOMIC_RELEASE, __HIP_MEMORY_SCOPE_AGENT);
            while (__hip_atomic_load(&a.flg[(ab*2 + (1-ahalf))*32], __ATOMIC_ACQUIRE, __HIP_MEMORY_SCOPE_AGENT) < (u32)(t+1))
                __builtin_amdgcn_s_sleep(1);
        }
        __syncthreads();
        if (tid < 64){
            float v = cloadf(spT + (ab*2)*SS + tid) + cloadf(spT + (ab*2 + 1)*SS + tid)
                    + ((a.mask[tid*BB + ab] > 0.f) ? 0.f : -1e9f);
            float m = v;
            #pragma unroll
            for (int off = 32; off; off >>= 1) m = fmaxf(m, __shfl_xor(m, off));
            float e = expf(v - m);
            float su = e;
            #pragma unroll
            for (int off = 32; off; off >>= 1) su += __shfl_xor(su, off);
            sal[tid] = e / su;
        }
        __syncthreads();
        int col = tid;
        const float* cbase = a.ctxf + (size_t)ab*H + ahalf*512 + col;
        float z = 0.f;
        #pragma unroll 8
        for (int s = 0; s < SS; s++)
            z += sal[s] * cbase[(size_t)s*BB*H];
        float zp = __shfl_xor(z, 1);
        if (!(tid & 1)){
            int j0 = ahalf*512 + col;
            u16 z0 = f2bf(z), z1 = f2bf(zp);
            cstore(a.ztHI + (size_t)t*HS + (size_t)ab*512 + (j0 >> 1), (u32)z0 | ((u32)z1 << 16));
            cstore(a.ztLO + (size_t)t*HS + (size_t)ab*512 + (j0 >> 1),
                   (u32)f2bf(z - bf2f(z0)) | ((u32)f2bf(zp - bf2f(z1)) << 16));
        }
        __syncthreads();
    };

    auto P4 = [&](int t){
        int jt = bid - 64;
        const u32* AbH = a.ztHI + (size_t)t*HS + (size_t)(wv*16 + r16)*512 + kq4;
        const u32* AbL = a.ztLO + (size_t)t*HS + (size_t)(wv*16 + r16)*512 + kq4;
        f32x4 ac0 = {}, ac1 = {}, ac2 = {};
        for (int k0 = 0; k0 < 32; k0++){
            bf16x8 ah = *(const bf16x8*)(AbH + k0*16);
            bf16x8 al = *(const bf16x8*)(AbL + k0*16);
            bf16x8 b0 = *(const bf16x8*)(wlds + (k0*64 + lane)*8);
            bf16x8 b1 = *(const bf16x8*)(wlds + 16384 + (k0*64 + lane)*8);
            bf16x8 b2 = *(const bf16x8*)(wlds + 32768 + (k0*64 + lane)*8);
            ac0 = MFMA(ah, b0, ac0, 0, 0, 0); ac0 = MFMA(al, b0, ac0, 0, 0, 0);
            ac1 = MFMA(ah, b1, ac1, 0, 0, 0); ac1 = MFMA(al, b1, ac1, 0, 0, 0);
            ac2 = MFMA(ah, b2, ac2, 0, 0, 0); ac2 = MFMA(al, b2, ac2, 0, 0, 0);
        }
        const u32* h1H = a.h1HI + (size_t)t*HS;
        const u32* h1L = a.h1LO + (size_t)t*HS;
        int sh = (r16 & 1)*16;
        #pragma unroll
        for (int r = 0; r < 4; r++){
            int b = wv*16 + rg + r, j = jt*16 + r16;
            float gr = ac0[r] + a.bih1[j];
            float gz = ac1[r] + a.bih1[H + j];
            float gn = ac2[r] + a.bih1[2*H + j];
            float hr = cloadf(a.ghF + (size_t)b*H3 + j)       + a.bhh1[j];
            float hz = cloadf(a.ghF + (size_t)b*H3 + H + j)   + a.bhh1[H + j];
            float hn = cloadf(a.ghF + (size_t)b*H3 + 2*H + j) + a.bhh1[2*H + j];
            u32 uh = h1H[(size_t)b*512 + (j >> 1)];
            u32 ul = h1L[(size_t)b*512 + (j >> 1)];
            float h1v = bf2f((u16)(uh >> sh)) + bf2f((u16)(ul >> sh));
            float rr = sigm(gr + hr), zz = sigm(gz + hz);
            float nn = tanhf(gn + rr*hn);
            float hv = (1.f - zz)*nn + zz*h1v;
            a.h2all[((size_t)t*BB + b)*H + j] = f2bf(hv);
            u16 hib = f2bf(hv);
            u16 lob = f2bf(hv - bf2f(hib));
            u32 hip = (u32)__shfl_xor((int)(u32)hib, 1);
            u32 lop = (u32)__shfl_xor((int)(u32)lob, 1);
            if (!(r16 & 1)){
                cstore(a.hsHI + (size_t)(t+1)*HS + (size_t)b*512 + (j >> 1), (u32)hib | (hip << 16));
                cstore(a.hsLO + (size_t)(t+1)*HS + (size_t)b*512 + (j >> 1), (u32)lob | (lop << 16));
            }
        }
    };

    // ---- role-specific dataflow loops ----
    if (bid < 64){
        for (int t = 0; t < TP; t++){
            cwait(sD, 64u*t, tid);               // hs[t] ready (t=0: trivially)
            P1(t);
            cprod(sA, tid);
            cwait(sB, 64u*(t+1), tid);           // proj ready
            P3(t);
            cprod(sC, tid);
        }
    } else if (bid < 128){
        for (int t = 0; t < TP; t++){
            cwait(sB, 64u*(t+1), tid);
            P3(t);
            cprod(sC, tid);
            cwait(sC, 256u*(t+1), tid);          // zt + gh1 complete
            P4(t);
            cprod(sD, tid);
        }
    } else if (bid < 192){
        for (int t = 0; t < TP; t++){
            cwait(sA, 64u*(t+1), tid);           // h1 ready
            P2gh1(t);
            cwait(sB, 64u*(t+1), tid);
            P3(t);
            cprod(sC, tid);                      // covers gh1 + zt stores
        }
    } else {
        for (int t = 0; t < TP; t++){
            cwait(sA, 64u*(t+1), tid);
            P2proj(t);
            cprod(sB, tid);
            cwait(sB, 64u*(t+1), tid);           // all proj cols ready
            P3(t);
            cprod(sC, tid);
        }
    }
}

// ---------- fused final GEMM + row-max (excl tgt) + s_true ----------
__global__ __launch_bounds__(256) void k_final(const u16* __restrict__ logitf, const u16* __restrict__ Wf,
                                               const int* __restrict__ y, float* __restrict__ pmax,
                                               float* __restrict__ strue){
    __shared__ float red[128][2];
    int tid = threadIdx.x, w = tid >> 6, lane = tid & 63;
    int wm = w >> 1, wn = w & 1;
    int row0 = blockIdx.x*128 + wm*64;
    int col0 = blockIdx.y*128 + wn*64;
    int r16 = lane & 15, rg = (lane >> 4)*4;
    f32x4 acc[4][4] = {};
    for (int k0 = 0; k0 < 16; k0++){
        bf16x8 af[4], bfv[4];
        #pragma unroll
        for (int i = 0; i < 4; i++)
            af[i] = *(const bf16x8*)(logitf + (((size_t)((row0 >> 4) + i)*16 + k0) << 9) + lane*8);
        #pragma unroll
        for (int j = 0; j < 4; j++)
            bfv[j] = *(const bf16x8*)(Wf + (((size_t)((col0 >> 4) + j)*16 + k0) << 9) + lane*8);
        #pragma unroll
        for (int i = 0; i < 4; i++)
            #pragma unroll
            for (int j = 0; j < 4; j++)
                acc[i][j] = MFMA(af[i], bfv[j], acc[i][j], 0, 0, 0);
    }
    #pragma unroll
    for (int i = 0; i < 4; i++){
        #pragma unroll
        for (int r = 0; r < 4; r++){
            int row = row0 + i*16 + rg + r;
            int tgt = y[row + BB];
            float m = -1e30f;
            #pragma unroll
            for (int j = 0; j < 4; j++){
                float v = acc[i][j][r];
                int col = col0 + j*16 + r16;
                if (col == tgt){ strue[row] = v; v = -1e30f; }
                m = fmaxf(m, v);
            }
            m = fmaxf(m, __shfl_xor(m, 1));
            m = fmaxf(m, __shfl_xor(m, 2));
            m = fmaxf(m, __shfl_xor(m, 4));
            m = fmaxf(m, __shfl_xor(m, 8));
            if (r16 == 0) red[wm*64 + i*16 + rg + r][wn] = m;
        }
    }
    __syncthreads();
    if (tid < 128){
        float m = fmaxf(red[tid][0], red[tid][1]);
        pmax[(size_t)(blockIdx.x*128 + tid)*VCHUNKS + blockIdx.y] = m;
    }
}

__global__ __launch_bounds__(256) void k_loss(const float* __restrict__ pmax, const float* __restrict__ strue,
                                              const int* __restrict__ y, float* __restrict__ out){
    int R = blockIdx.x*256 + threadIdx.x;
    int lane = threadIdx.x & 63, wave = threadIdx.x >> 6;
    float l = 0.f;
    if (R < NROWS){
        int tgt = y[R + BB];
        if (tgt != 0){
            const float* pm = pmax + (size_t)R*VCHUNKS;
            float m = -1e30f;
            for (int i = 0; i < VCHUNKS; i++) m = fmaxf(m, pm[i]);
            l = fmaxf(FMARGIN - strue[R] + m, 0.f);
        }
    }
    #pragma unroll
    for (int off = 32; off; off >>= 1) l += __shfl_down(l, off);
    __shared__ float wsum[4];
    if (lane == 0) wsum[wave] = l;
    __syncthreads();
    if (threadIdx.x == 0) atomicAdd(out, wsum[0] + wsum[1] + wsum[2] + wsum[3]);
}

// ---------- launch ----------
extern "C" void kernel_launch(void* const* d_in, const int* in_sizes, int n_in,
                              void* d_out, int out_size, void* d_ws, size_t ws_size,
                              hipStream_t stream){
    const float* ctx    = (const float*)d_in[0];
    const float* mask   = (const float*)d_in[1];
    const int*   y      = (const int*)d_in[2];
    const float* emb_W  = (const float*)d_in[3];
    const float* W_init = (const float*)d_in[4];
    const float* b_init = (const float*)d_in[5];
    const float* W_ih0  = (const float*)d_in[6];
    const float* W_hh0  = (const float*)d_in[7];
    const float* b_ih0  = (const float*)d_in[8];
    const float* b_hh0  = (const float*)d_in[9];
    const float* W_c2c  = (const float*)d_in[10];
    const float* W_h2c  = (const float*)d_in[11];
    const float* v_att  = (const float*)d_in[12];
    const float* W_ih1  = (const float*)d_in[13];
    const float* W_hh1  = (const float*)d_in[14];
    const float* b_ih1  = (const float*)d_in[15];
    const float* b_hh1  = (const float*)d_in[16];
    const float* W_h2o  = (const float*)d_in[17];
    const float* b_h2o  = (const float*)d_in[18];
    const float* W_out  = (const float*)d_in[19];
    float* out = (float*)d_out;

    char* wsb = (char*)d_ws;
    size_t off = 0;
    auto alloc = [&](size_t bytes)->void*{
        void* p = (void*)(wsb + off);
        off = (off + bytes + 255) & ~(size_t)255;
        return p;
    };
    u16* Wih0f = (u16*)alloc((size_t)H3*DIN*2);
    u16* Whh0f = (u16*)alloc((size_t)H3*H*2);
    u16* Wih1f = (u16*)alloc((size_t)H3*H*2);
    u16* Whh1f = (u16*)alloc((size_t)H3*H*2);
    u16* Wh2cf = (u16*)alloc((size_t)H*H*2);
    u16* Wc2cf = (u16*)alloc((size_t)H*H*2);
    u16* Wh2of = (u16*)alloc((size_t)DIN*H*2);
    u16* Woutf = (u16*)alloc((size_t)VSZ*DIN*2);     // during recurrence: prF alias
    u16* ctxb  = (u16*)alloc((size_t)SS*BB*H*2);
    u16* ctxpb = (u16*)alloc((size_t)SS*BB*H*2);
    u16* embf  = (u16*)alloc((size_t)NROWS*DIN*2);
    u16* gi0b  = (u16*)alloc((size_t)NROWS*H3*2);    // reused after recurrence
    u16* h2allb= (u16*)alloc((size_t)NROWS*H*2);
    u32* hsHI  = (u32*)alloc((size_t)(TP+1)*HS*4);
    u32* hsLO  = (u32*)alloc((size_t)(TP+1)*HS*4);
    u32* h1HI  = (u32*)alloc((size_t)TP*HS*4);
    u32* h1LO  = (u32*)alloc((size_t)TP*HS*4);
    u32* ztHI  = (u32*)alloc((size_t)TP*HS*4);
    u32* ztLO  = (u32*)alloc((size_t)TP*HS*4);
    float* ghF = (float*)alloc((size_t)BB*H3*4);
    float* spar= (float*)alloc((size_t)TP*256*SS*4);   // 3 MB partial scores
    u32* bar   = (u32*)alloc(8192);
    u32* flg   = (u32*)alloc(32768);
    float* strue  = (float*)alloc(NROWS*4);
    float* msum   = (float*)alloc(BB*4);
    float* meanc  = (float*)alloc((size_t)BB*H*4);
    float* h0f    = (float*)alloc((size_t)BB*H*4);

    float* prF = (float*)Woutf;      // Woutf recomputed after recurrence

    float* logitf  = (float*)gi0b;
    u16*   logitfr = (u16*)(gi0b + (size_t)NROWS*DIN*2);
    float* pmax    = (float*)(gi0b + (size_t)NROWS*DIN*2 + (size_t)NROWS*DIN);

    hipMemsetAsync(d_out, 0, sizeof(float), stream);
    hipMemsetAsync(bar, 0, 8192, stream);
    hipMemsetAsync(flg, 0, 32768, stream);

    // ---- init ----
    hipLaunchKernelGGL(k_mask_sum, dim3(1), dim3(128), 0, stream, mask, msum);
    hipLaunchKernelGGL(k_mean_ctx, dim3(BB*H/256), dim3(256), 0, stream, ctx, msum, meanc);
    hipLaunchKernelGGL((k_gemm_nt<1>), dim3(H/64, BB/64), dim3(256), 0, stream,
                       meanc, W_init, b_init, h0f, BB, H, H);
    hipLaunchKernelGGL(k_pack_h0, dim3(HS/256), dim3(256), 0, stream, h0f, hsHI, hsLO);

    hipLaunchKernelGGL(k_f2bf_frag, dim3(H3*DIN/8/256), dim3(256), 0, stream, W_ih0, Wih0f, H3*DIN/8, DIN/8);
    hipLaunchKernelGGL(k_f2bf_frag, dim3(H3*H/8/256), dim3(256), 0, stream, W_hh0, Whh0f, H3*H/8, H/8);
    hipLaunchKernelGGL(k_f2bf_frag, dim3(H3*H/8/256), dim3(256), 0, stream, W_ih1, Wih1f, H3*H/8, H/8);
    hipLaunchKernelGGL(k_f2bf_frag, dim3(H3*H/8/256), dim3(256), 0, stream, W_hh1, Whh1f, H3*H/8, H/8);
    hipLaunchKernelGGL(k_f2bf_frag, dim3(H*H/8/256), dim3(256), 0, stream, W_h2c, Wh2cf, H*H/8, H/8);
    hipLaunchKernelGGL(k_f2bf_frag, dim3(H*H/8/256), dim3(256), 0, stream, W_c2c, Wc2cf, H*H/8, H/8);
    hipLaunchKernelGGL(k_f2bf_frag, dim3(DIN*H/8/256), dim3(256), 0, stream, W_h2o, Wh2of, DIN*H/8, H/8);
    hipLaunchKernelGGL(k_f32bf, dim3(SS*BB*H/4/256), dim3(256), 0, stream, ctx, ctxb, SS*BB*H/4);
    hipLaunchKernelGGL(k_emb_frag, dim3(NROWS/4), dim3(256), 0, stream, emb_W, y, embf);

    // ---- batched GEMMs ----
    hipLaunchKernelGGL((k_gemmf<1,0,u16>), dim3(H3/128, NROWS/128), dim3(256), 0, stream,
                       embf, Wih0f, b_ih0, gi0b, NROWS, H3, DIN);
    hipLaunchKernelGGL((k_gemmf<0,0,u16>), dim3(H/128, SS*BB/128), dim3(256), 0, stream,
                       ctxb, Wc2cf, (const float*)nullptr, ctxpb, SS*BB, H, H);

    // ---- persistent recurrence ----
    RK rk;
    rk.gi0 = gi0b; rk.Whh0 = Whh0f; rk.Wh2c = Wh2cf; rk.Wih1 = Wih1f; rk.Whh1 = Whh1f;
    rk.ctxp = ctxpb;
    rk.bhh0 = b_hh0; rk.bih1 = b_ih1; rk.bhh1 = b_hh1; rk.vatt = v_att; rk.mask = mask; rk.ctxf = ctx;
    rk.hsHI = hsHI; rk.hsLO = hsLO; rk.h1HI = h1HI; rk.h1LO = h1LO; rk.ztHI = ztHI; rk.ztLO = ztLO;
    rk.prF = prF; rk.ghF = ghF; rk.spar = spar; rk.flg = flg;
    rk.h2all = h2allb; rk.bar = bar;
    void* kp[] = { (void*)&rk };
    hipLaunchCooperativeKernel((const void*)k_recur10, dim3(NBLK), dim3(512), kp, 0, stream);

    // ---- output head (Woutf recomputed now that prF alias is dead) ----
    hipLaunchKernelGGL(k_rownorm_frag, dim3(VSZ/4), dim3(256), 0, stream, W_out, Woutf, VSZ);
    hipLaunchKernelGGL((k_gemmf<0,1,float>), dim3(DIN/128, NROWS/128), dim3(256), 0, stream,
                       h2allb, Wh2of, b_h2o, logitf, NROWS, DIN, H);
    hipLaunchKernelGGL(k_rownorm_frag, dim3(NROWS/4), dim3(256), 0, stream, logitf, logitfr, NROWS);
    hipLaunchKernelGGL(k_final, dim3(NROWS/128, VSZ/128), dim3(256), 0, stream,
                       logitfr, Woutf, y, pmax, strue);
    hipLaunchKernelGGL(k_loss, dim3((NROWS + 255)/256), dim3(256), 0, stream, pmax, strue, y, out);
}

// Round 17
// 4655.629 us; speedup vs baseline: 2.7156x; 2.7156x over previous
//
#include <hip/hip_runtime.h>
#include <math.h>

#define H    1024
#define H3   3072
#define DIN  512
#define VSZ  32000
#define SS   64
#define BB   128
#define TP   47
#define NROWS (TP*BB)      // 6016
#define VCHUNKS 250        // 32000 / 128
#define FMARGIN 0.1f
#define NBLK 256
#define HS   65536         // u32 per packed state step (128*1024/2)
#define CTXPL_S 62         // ctxp rows pinned in LDS (s=62,63 from global)

typedef unsigned short u16;
typedef unsigned int u32;
typedef unsigned long long u64;
typedef __bf16 bf16_t;
typedef bf16_t bf16x8 __attribute__((ext_vector_type(8)));
typedef float f32x4 __attribute__((ext_vector_type(4)));
typedef u16 u16x4 __attribute__((ext_vector_type(4)));
typedef u16 u16x8 __attribute__((ext_vector_type(8)));

#define MFMA __builtin_amdgcn_mfma_f32_16x16x32_bf16

__device__ inline u16 f2bf(float f){
    unsigned b = __float_as_uint(f);
    return (u16)((b + 0x7FFFu + ((b >> 16) & 1u)) >> 16);
}
__device__ inline float bf2f(u16 u){ return __uint_as_float(((unsigned)u) << 16); }
__device__ inline float sigm(float x){ return 1.f/(1.f + expf(-x)); }

__device__ inline void stoval(float* p, float v){ *p = v; }
__device__ inline void stoval(u16* p, float v){ *p = f2bf(v); }

__device__ inline void cstore(u32* p, u32 v){ __hip_atomic_store(p, v, __ATOMIC_RELAXED, __HIP_MEMORY_SCOPE_AGENT); }
__device__ inline void cstoref(float* p, float v){ __hip_atomic_store(p, v, __ATOMIC_RELAXED, __HIP_MEMORY_SCOPE_AGENT); }
__device__ inline void cstore64(u64* p, u64 v){ __hip_atomic_store(p, v, __ATOMIC_RELAXED, __HIP_MEMORY_SCOPE_AGENT); }
__device__ inline float cloadf(const float* p){ return __hip_atomic_load(p, __ATOMIC_RELAXED, __HIP_MEMORY_SCOPE_AGENT); }

// tree grid barrier; counters @64..1056, release lines @1536..1760 (no overlap; bar=2048 u32)
__device__ inline void gbar(u32* bar, u32* mygen, int tid, int bid){
    __syncthreads();
    if (tid == 0){
        u32 tgt = ++(*mygen);
        __builtin_amdgcn_s_waitcnt(0);
        u32* cnt = bar + 64 + (bid >> 3)*32;
        u32 old = __hip_atomic_fetch_add(cnt, 1u, __ATOMIC_RELAXED, __HIP_MEMORY_SCOPE_AGENT);
        if (old == 7u){
            __hip_atomic_store(cnt, 0u, __ATOMIC_RELAXED, __HIP_MEMORY_SCOPE_AGENT);
            u32 old2 = __hip_atomic_fetch_add(&bar[1], 1u, __ATOMIC_RELEASE, __HIP_MEMORY_SCOPE_AGENT);
            if (old2 == 31u){
                __hip_atomic_store(&bar[1], 0u, __ATOMIC_RELAXED, __HIP_MEMORY_SCOPE_AGENT);
                #pragma unroll
                for (int x = 0; x < 8; x++)
                    __hip_atomic_store(&bar[1536 + x*32], tgt, __ATOMIC_RELEASE, __HIP_MEMORY_SCOPE_AGENT);
            }
        }
        u32* rel = &bar[1536 + (bid & 7)*32];
        while (__hip_atomic_load(rel, __ATOMIC_RELAXED, __HIP_MEMORY_SCOPE_AGENT) < tgt)
            __builtin_amdgcn_s_sleep(2);
    }
    __syncthreads();
    asm volatile("" ::: "memory");
}

// ---------- init helpers ----------

__global__ __launch_bounds__(128) void k_mask_sum(const float* __restrict__ mask, float* __restrict__ msum){
    int b = threadIdx.x;
    if (b < BB){ float s = 0.f; for (int i = 0; i < SS; i++) s += mask[i*BB + b]; msum[b] = s; }
}

__global__ __launch_bounds__(256) void k_mean_ctx(const float* __restrict__ ctx, const float* __restrict__ msum,
                                                  float* __restrict__ mean){
    int idx = blockIdx.x*256 + threadIdx.x;
    if (idx < BB*H){
        float s = 0.f;
        for (int i = 0; i < SS; i++) s += ctx[(size_t)i*BB*H + idx];
        mean[idx] = s / msum[idx / H];
    }
}

__global__ __launch_bounds__(256) void k_f32bf(const float* __restrict__ in, u16* __restrict__ out, int n4){
    int i = blockIdx.x*256 + threadIdx.x;
    if (i >= n4) return;
    float4 v = ((const float4*)in)[i];
    u16x4 o = { f2bf(v.x), f2bf(v.y), f2bf(v.z), f2bf(v.w) };
    ((u16x4*)out)[i] = o;
}

__global__ __launch_bounds__(256) void k_pack_h0(const float* __restrict__ h0, u32* __restrict__ hsHI,
                                                 u32* __restrict__ hsLO){
    int i = blockIdx.x*256 + threadIdx.x;    // < 65536
    float v0 = h0[i*2], v1 = h0[i*2 + 1];
    u16 a = f2bf(v0), b = f2bf(v1);
    hsHI[i] = (u32)a | ((u32)b << 16);
    hsLO[i] = (u32)f2bf(v0 - bf2f(a)) | ((u32)f2bf(v1 - bf2f(b)) << 16);
}

__global__ __launch_bounds__(256) void k_f2bf_frag(const float* __restrict__ in, u16* __restrict__ out,
                                                   int RK8, int K8){
    int t = blockIdx.x*256 + threadIdx.x;
    if (t >= RK8) return;
    int r = t / K8, k8 = t - r*K8;
    const float* p = in + (size_t)r*K8*8 + k8*8;
    float4 a = *(const float4*)p;
    float4 b = *(const float4*)(p + 4);
    size_t dst = ((size_t)(r >> 4)*(K8 >> 2) + (k8 >> 2))*512 + (size_t)((r & 15) + (k8 & 3)*16)*8;
    u16x8 o;
    o[0]=f2bf(a.x); o[1]=f2bf(a.y); o[2]=f2bf(a.z); o[3]=f2bf(a.w);
    o[4]=f2bf(b.x); o[5]=f2bf(b.y); o[6]=f2bf(b.z); o[7]=f2bf(b.w);
    *(u16x8*)(out + dst) = o;
}

__global__ __launch_bounds__(256) void k_rownorm_frag(const float* __restrict__ in, u16* __restrict__ out,
                                                      int nrows){
    int w = threadIdx.x >> 6, lane = threadIdx.x & 63;
    int row = blockIdx.x*4 + w;
    if (row >= nrows) return;
    const float* r = in + (size_t)row*512 + lane*8;
    float4 a = *(const float4*)r;
    float4 b = *(const float4*)(r + 4);
    float s = a.x*a.x + a.y*a.y + a.z*a.z + a.w*a.w
            + b.x*b.x + b.y*b.y + b.z*b.z + b.w*b.w;
    #pragma unroll
    for (int off = 32; off; off >>= 1) s += __shfl_xor(s, off);
    float inv = rsqrtf(s);
    size_t dst = ((size_t)(row >> 4)*16 + (lane >> 2))*512 + (size_t)((row & 15) + (lane & 3)*16)*8;
    u16x8 o;
    o[0]=f2bf(a.x*inv); o[1]=f2bf(a.y*inv); o[2]=f2bf(a.z*inv); o[3]=f2bf(a.w*inv);
    o[4]=f2bf(b.x*inv); o[5]=f2bf(b.y*inv); o[6]=f2bf(b.z*inv); o[7]=f2bf(b.w*inv);
    *(u16x8*)(out + dst) = o;
}

__global__ __launch_bounds__(256) void k_emb_frag(const float* __restrict__ emb, const int* __restrict__ y,
                                                  u16* __restrict__ out){
    int w = threadIdx.x >> 6, lane = threadIdx.x & 63;
    int row = blockIdx.x*4 + w;            // < 6016
    int src = y[row];
    const float* r = emb + (size_t)src*512 + lane*8;
    float4 a = *(const float4*)r;
    float4 b = *(const float4*)(r + 4);
    size_t dst = ((size_t)(row >> 4)*16 + (lane >> 2))*512 + (size_t)((row & 15) + (lane & 3)*16)*8;
    u16x8 o;
    o[0]=f2bf(a.x); o[1]=f2bf(a.y); o[2]=f2bf(a.z); o[3]=f2bf(a.w);
    o[4]=f2bf(b.x); o[5]=f2bf(b.y); o[6]=f2bf(b.z); o[7]=f2bf(b.w);
    *(u16x8*)(out + dst) = o;
}

// ---------- fp32 GEMM (h0 init only) ----------
template<int ACT>
__global__ __launch_bounds__(256) void k_gemm_nt(const float* __restrict__ A, const float* __restrict__ W,
                                                 const float* __restrict__ bias, float* __restrict__ C,
                                                 int M, int N, int K){
    __shared__ float As[16][68];
    __shared__ float Ws[16][68];
    int tid = threadIdx.x;
    int bm = blockIdx.y*64, bn = blockIdx.x*64;
    int lr = tid >> 2;
    int lk = (tid & 3) * 4;
    int tr = (tid >> 4) * 4;
    int tc = (tid & 15) * 4;
    float acc[4][4] = {};
    const float* Abase = A + (size_t)(bm + lr)*K;
    const float* Wbase = W + (size_t)(bn + lr)*K;
    for (int k0 = 0; k0 < K; k0 += 16){
        float4 av = *(const float4*)(Abase + k0 + lk);
        float4 wv = *(const float4*)(Wbase + k0 + lk);
        __syncthreads();
        As[lk+0][lr]=av.x; As[lk+1][lr]=av.y; As[lk+2][lr]=av.z; As[lk+3][lr]=av.w;
        Ws[lk+0][lr]=wv.x; Ws[lk+1][lr]=wv.y; Ws[lk+2][lr]=wv.z; Ws[lk+3][lr]=wv.w;
        __syncthreads();
        #pragma unroll
        for (int kk = 0; kk < 16; kk++){
            float4 a = *(const float4*)&As[kk][tr];
            float4 w = *(const float4*)&Ws[kk][tc];
            acc[0][0] += a.x*w.x; acc[0][1] += a.x*w.y; acc[0][2] += a.x*w.z; acc[0][3] += a.x*w.w;
            acc[1][0] += a.y*w.x; acc[1][1] += a.y*w.y; acc[1][2] += a.y*w.z; acc[1][3] += a.y*w.w;
            acc[2][0] += a.z*w.x; acc[2][1] += a.z*w.y; acc[2][2] += a.z*w.z; acc[2][3] += a.z*w.w;
            acc[3][0] += a.w*w.x; acc[3][1] += a.w*w.y; acc[3][2] += a.w*w.z; acc[3][3] += a.w*w.w;
        }
    }
    #pragma unroll
    for (int i = 0; i < 4; i++){
        #pragma unroll
        for (int j = 0; j < 4; j++){
            float v = acc[i][j];
            if (bias) v += bias[bn + tc + j];
            if (ACT == 1) v = tanhf(v);
            C[(size_t)(bm + tr + i)*N + bn + tc + j] = v;
        }
    }
}

// ---------- batched bf16 MFMA GEMM ----------
template<int AFRAG, int ACT, typename OutT>
__global__ __launch_bounds__(256) void k_gemmf(const u16* __restrict__ A, const u16* __restrict__ B,
                                               const float* __restrict__ bias, OutT* __restrict__ C,
                                               int M, int N, int K){
    int tid = threadIdx.x, lane = tid & 63, w = tid >> 6;
    int wm = w >> 1, wn = w & 1;
    int row0 = blockIdx.y*128 + wm*64, col0 = blockIdx.x*128 + wn*64;
    int r16 = lane & 15, kg8 = (lane >> 4)*8, rg = (lane >> 4)*4;
    int K32 = K >> 5;
    f32x4 acc[4][4] = {};
    for (int k0 = 0; k0 < K32; k0++){
        bf16x8 af[4], bfv[4];
        #pragma unroll
        for (int i = 0; i < 4; i++){
            if (AFRAG) af[i] = *(const bf16x8*)(A + (((size_t)((row0 >> 4) + i)*K32 + k0) << 9) + lane*8);
            else       af[i] = *(const bf16x8*)(A + (size_t)(row0 + i*16 + r16)*K + k0*32 + kg8);
        }
        #pragma unroll
        for (int j = 0; j < 4; j++)
            bfv[j] = *(const bf16x8*)(B + (((size_t)((col0 >> 4) + j)*K32 + k0) << 9) + lane*8);
        #pragma unroll
        for (int i = 0; i < 4; i++)
            #pragma unroll
            for (int j = 0; j < 4; j++)
                acc[i][j] = MFMA(af[i], bfv[j], acc[i][j], 0, 0, 0);
    }
    #pragma unroll
    for (int i = 0; i < 4; i++){
        #pragma unroll
        for (int j = 0; j < 4; j++){
            #pragma unroll
            for (int r = 0; r < 4; r++){
                int row = row0 + i*16 + rg + r;
                int col = col0 + j*16 + r16;
                float v = acc[i][j][r];
                if (bias) v += bias[col];
                if (ACT) v = tanhf(v);
                stoval(C + (size_t)row*N + col, v);
            }
        }
    }
}

// ---------- persistent recurrence: 4 global barriers + pairwise score sync ----------
struct RJ {
    const u16 *gi0, *Whh0, *Wh2c, *Wih1, *Whh1, *ctxp;
    const float *bhh0, *bih1, *bhh1, *vatt, *mask, *ctxf;
    u32 *hsHI, *hsLO, *h1HI, *h1LO, *ztHI, *ztLO;
    float *prF;    // per-step (aliased on Woutf)
    float *ghF;    // single BB*H3, atomic-consumed
    float *spar;   // per-step partial scores: spar + t*256*64
    u32 *flg;      // pairwise flags, 256 lines of 32 u32
    u16 *h2all;
    u32 *bar;
};

__global__ __launch_bounds__(512) void k_recur9(RJ a){
    __shared__ u16 wlds[49152];            // 96 KB weights
    __shared__ u16 ctxpL[CTXPL_S*512];     // 62 KB ctxp (b,half) slice
    __shared__ float sal[SS];
    const int tid = threadIdx.x, lane = tid & 63, wv = tid >> 6;
    const int bid = blockIdx.x;
    const int r16 = lane & 15, rg = (lane >> 4)*4, kq4 = (lane >> 4)*4;
    const int ab = (bid & 7)*16 + ((bid >> 3) >> 1);
    const int ahalf = (bid >> 3) & 1;
    u32 mygen = 0;

    {   // weight slices -> LDS
        auto cp32k = [&](const u16* gsrc, int tile, int base){
            const u32* s = (const u32*)(gsrc + (size_t)tile*16384);
            u32* d = (u32*)(wlds + base);
            #pragma unroll
            for (int i = 0; i < 16; i++) d[tid + i*512] = s[tid + i*512];
        };
        if (bid < 64){
            cp32k(a.Whh0, bid, 0); cp32k(a.Whh0, 64+bid, 16384); cp32k(a.Whh0, 128+bid, 32768);
        } else if (bid < 128){
            int jt = bid - 64;
            cp32k(a.Wih1, jt, 0); cp32k(a.Wih1, 64+jt, 16384); cp32k(a.Wih1, 128+jt, 32768);
        } else if (bid < 192){
            int wt = bid - 128;
            cp32k(a.Whh1, 3*wt, 0); cp32k(a.Whh1, 3*wt+1, 16384); cp32k(a.Whh1, 3*wt+2, 32768);
        } else {
            cp32k(a.Wh2c, bid-192, 0);
        }
        for (int i = tid; i < CTXPL_S*512/8; i += 512){
            int s = (i*8) >> 9, h = (i*8) & 511;
            *(u16x8*)(ctxpL + i*8) = *(const u16x8*)(a.ctxp + ((size_t)(s*BB + ab))*H + ahalf*512 + h);
        }
    }
    float vv[8];
    {
        float4 v0 = *(const float4*)(a.vatt + ahalf*512 + lane*8);
        float4 v1 = *(const float4*)(a.vatt + ahalf*512 + lane*8 + 4);
        vv[0]=v0.x; vv[1]=v0.y; vv[2]=v0.z; vv[3]=v0.w;
        vv[4]=v1.x; vv[5]=v1.y; vv[6]=v1.z; vv[7]=v1.w;
    }
    __syncthreads();

    for (int t = 0; t < TP; t++){
        float* prT = a.prF + (size_t)t*BB*H;
        float* spT = a.spar + (size_t)t*256*SS;

        // ---- P1: GRU0 GEMM+combine (blocks 0..63) ----
        if (bid < 64){
            const u32* AbH = a.hsHI + (size_t)t*HS + (size_t)(wv*16 + r16)*512 + kq4;
            const u32* AbL = a.hsLO + (size_t)t*HS + (size_t)(wv*16 + r16)*512 + kq4;
            f32x4 ac0 = {}, ac1 = {}, ac2 = {};
            for (int k0 = 0; k0 < 32; k0++){
                bf16x8 ah = *(const bf16x8*)(AbH + k0*16);
                bf16x8 al = *(const bf16x8*)(AbL + k0*16);
                bf16x8 b0 = *(const bf16x8*)(wlds + (k0*64 + lane)*8);
                bf16x8 b1 = *(const bf16x8*)(wlds + 16384 + (k0*64 + lane)*8);
                bf16x8 b2 = *(const bf16x8*)(wlds + 32768 + (k0*64 + lane)*8);
                ac0 = MFMA(ah, b0, ac0, 0, 0, 0); ac0 = MFMA(al, b0, ac0, 0, 0, 0);
                ac1 = MFMA(ah, b1, ac1, 0, 0, 0); ac1 = MFMA(al, b1, ac1, 0, 0, 0);
                ac2 = MFMA(ah, b2, ac2, 0, 0, 0); ac2 = MFMA(al, b2, ac2, 0, 0, 0);
            }
            const u16* gi = a.gi0 + (size_t)t*BB*H3;
            const u32* hsH = a.hsHI + (size_t)t*HS;
            const u32* hsL = a.hsLO + (size_t)t*HS;
            int sh = (r16 & 1)*16;
            #pragma unroll
            for (int r = 0; r < 4; r++){
                int b = wv*16 + rg + r, j = bid*16 + r16;
                float gr = bf2f(gi[(size_t)b*H3 + j]);
                float gz = bf2f(gi[(size_t)b*H3 + H + j]);
                float gn = bf2f(gi[(size_t)b*H3 + 2*H + j]);
                float hr = ac0[r] + a.bhh0[j];
                float hz = ac1[r] + a.bhh0[H + j];
                float hn = ac2[r] + a.bhh0[2*H + j];
                u32 uh = hsH[(size_t)b*512 + (j >> 1)];
                u32 ul = hsL[(size_t)b*512 + (j >> 1)];
                float hp = bf2f((u16)(uh >> sh)) + bf2f((u16)(ul >> sh));
                float rr = sigm(gr + hr), zz = sigm(gz + hz);
                float nn = tanhf(gn + rr*hn);
                float hv = (1.f - zz)*nn + zz*hp;
                u16 hib = f2bf(hv);
                u16 lob = f2bf(hv - bf2f(hib));
                u32 hip = (u32)__shfl_xor((int)(u32)hib, 1);
                u32 lop = (u32)__shfl_xor((int)(u32)lob, 1);
                if (!(r16 & 1)){
                    cstore(a.h1HI + (size_t)t*HS + (size_t)b*512 + (j >> 1), (u32)hib | (hip << 16));
                    cstore(a.h1LO + (size_t)t*HS + (size_t)b*512 + (j >> 1), (u32)lob | (lop << 16));
                }
            }
        }
        gbar(a.bar, &mygen, tid, bid);

        // ---- P2: gh1 (128..191) || proj (192..255) ----
        if (bid >= 128){
            const u32* AbH = a.h1HI + (size_t)t*HS + (size_t)(wv*16 + r16)*512 + kq4;
            const u32* AbL = a.h1LO + (size_t)t*HS + (size_t)(wv*16 + r16)*512 + kq4;
            if (bid < 192){
                int wt = bid - 128;
                f32x4 ac0 = {}, ac1 = {}, ac2 = {};
                for (int k0 = 0; k0 < 32; k0++){
                    bf16x8 ah = *(const bf16x8*)(AbH + k0*16);
                    bf16x8 al = *(const bf16x8*)(AbL + k0*16);
                    bf16x8 b0 = *(const bf16x8*)(wlds + (k0*64 + lane)*8);
                    bf16x8 b1 = *(const bf16x8*)(wlds + 16384 + (k0*64 + lane)*8);
                    bf16x8 b2 = *(const bf16x8*)(wlds + 32768 + (k0*64 + lane)*8);
                    ac0 = MFMA(ah, b0, ac0, 0, 0, 0); ac0 = MFMA(al, b0, ac0, 0, 0, 0);
                    ac1 = MFMA(ah, b1, ac1, 0, 0, 0); ac1 = MFMA(al, b1, ac1, 0, 0, 0);
                    ac2 = MFMA(ah, b2, ac2, 0, 0, 0); ac2 = MFMA(al, b2, ac2, 0, 0, 0);
                }
                #pragma unroll
                for (int r = 0; r < 4; r++){
                    int b = wv*16 + rg + r;
                    int c0 = wt*48 + r16;
                    float p0 = __shfl_xor(ac0[r], 1);
                    float p1 = __shfl_xor(ac1[r], 1);
                    float p2 = __shfl_xor(ac2[r], 1);
                    if (!(r16 & 1)){
                        cstore64((u64*)(a.ghF + (size_t)b*H3 + c0),
                                 (u64)__float_as_uint(ac0[r]) | ((u64)__float_as_uint(p0) << 32));
                        cstore64((u64*)(a.ghF + (size_t)b*H3 + c0 + 16),
                                 (u64)__float_as_uint(ac1[r]) | ((u64)__float_as_uint(p1) << 32));
                        cstore64((u64*)(a.ghF + (size_t)b*H3 + c0 + 32),
                                 (u64)__float_as_uint(ac2[r]) | ((u64)__float_as_uint(p2) << 32));
                    }
                }
            } else {
                f32x4 ac = {};
                for (int k0 = 0; k0 < 32; k0++){
                    bf16x8 ah = *(const bf16x8*)(AbH + k0*16);
                    bf16x8 al = *(const bf16x8*)(AbL + k0*16);
                    bf16x8 bv = *(const bf16x8*)(wlds + (k0*64 + lane)*8);
                    ac = MFMA(ah, bv, ac, 0, 0, 0); ac = MFMA(al, bv, ac, 0, 0, 0);
                }
                #pragma unroll
                for (int r = 0; r < 4; r++){
                    int b = wv*16 + rg + r;
                    int c0 = (bid - 192)*16 + r16;
                    float p0 = __shfl_xor(ac[r], 1);
                    if (!(r16 & 1))
                        cstore64((u64*)(prT + (size_t)b*H + c0),
                                 (u64)__float_as_uint(ac[r]) | ((u64)__float_as_uint(p0) << 32));
                }
            }
        }
        gbar(a.bar, &mygen, tid, bid);

        // ---- P3 (fused): partial scores -> pairwise sync -> softmax + z_t ----
        {
            float pj[8];
            {
                float4 q0 = *(const float4*)(prT + (size_t)ab*H + ahalf*512 + lane*8);
                float4 q1 = *(const float4*)(prT + (size_t)ab*H + ahalf*512 + lane*8 + 4);
                pj[0]=q0.x; pj[1]=q0.y; pj[2]=q0.z; pj[3]=q0.w;
                pj[4]=q1.x; pj[5]=q1.y; pj[6]=q1.z; pj[7]=q1.w;
            }
            #pragma unroll
            for (int q = 0; q < 8; q++){
                int s = wv*8 + q;
                u16x8 cv;
                if (s < CTXPL_S) cv = *(const u16x8*)(ctxpL + s*512 + lane*8);
                else cv = *(const u16x8*)(a.ctxp + ((size_t)(s*BB + ab))*H + ahalf*512 + lane*8);
                float acc = 0.f;
                #pragma unroll
                for (int e = 0; e < 8; e++) acc += tanhf(bf2f(cv[e]) + pj[e]) * vv[e];
                #pragma unroll
                for (int off = 32; off; off >>= 1) acc += __shfl_xor(acc, off);
                if (lane == 0) cstoref(spT + (ab*2 + ahalf)*SS + s, acc);
            }
            // pairwise release/acquire with partner block (same b, other half)
            __syncthreads();
            if (tid == 0){
                __builtin_amdgcn_s_waitcnt(0);
                __hip_atomic_store(&a.flg[(ab*2 + ahalf)*32], (u32)(t+1), __ATOMIC_RELEASE, __HIP_MEMORY_SCOPE_AGENT);
                while (__hip_atomic_load(&a.flg[(ab*2 + (1-ahalf))*32], __ATOMIC_ACQUIRE, __HIP_MEMORY_SCOPE_AGENT) < (u32)(t+1))
                    __builtin_amdgcn_s_sleep(1);
            }
            __syncthreads();
            // softmax + z_t
            if (tid < 64){
                float v = cloadf(spT + (ab*2)*SS + tid) + cloadf(spT + (ab*2 + 1)*SS + tid)
                        + ((a.mask[tid*BB + ab] > 0.f) ? 0.f : -1e9f);
                float m = v;
                #pragma unroll
                for (int off = 32; off; off >>= 1) m = fmaxf(m, __shfl_xor(m, off));
                float e = expf(v - m);
                float su = e;
                #pragma unroll
                for (int off = 32; off; off >>= 1) su += __shfl_xor(su, off);
                sal[tid] = e / su;
            }
            __syncthreads();
            int col = tid;   // 0..511 within half
            const float* cbase = a.ctxf + (size_t)ab*H + ahalf*512 + col;
            float z = 0.f;
            #pragma unroll 8
            for (int s = 0; s < SS; s++)
                z += sal[s] * cbase[(size_t)s*BB*H];
            float zp = __shfl_xor(z, 1);
            if (!(tid & 1)){
                int j0 = ahalf*512 + col;
                u16 z0 = f2bf(z), z1 = f2bf(zp);
                cstore(a.ztHI + (size_t)t*HS + (size_t)ab*512 + (j0 >> 1), (u32)z0 | ((u32)z1 << 16));
                cstore(a.ztLO + (size_t)t*HS + (size_t)ab*512 + (j0 >> 1),
                       (u32)f2bf(z - bf2f(z0)) | ((u32)f2bf(zp - bf2f(z1)) << 16));
            }
            __syncthreads();
        }
        gbar(a.bar, &mygen, tid, bid);

        // ---- P4: GRU1 GEMM+combine (blocks 64..127) ----
        if (bid >= 64 && bid < 128){
            int jt = bid - 64;
            const u32* AbH = a.ztHI + (size_t)t*HS + (size_t)(wv*16 + r16)*512 + kq4;
            const u32* AbL = a.ztLO + (size_t)t*HS + (size_t)(wv*16 + r16)*512 + kq4;
            f32x4 ac0 = {}, ac1 = {}, ac2 = {};
            for (int k0 = 0; k0 < 32; k0++){
                bf16x8 ah = *(const bf16x8*)(AbH + k0*16);
                bf16x8 al = *(const bf16x8*)(AbL + k0*16);
                bf16x8 b0 = *(const bf16x8*)(wlds + (k0*64 + lane)*8);
                bf16x8 b1 = *(const bf16x8*)(wlds + 16384 + (k0*64 + lane)*8);
                bf16x8 b2 = *(const bf16x8*)(wlds + 32768 + (k0*64 + lane)*8);
                ac0 = MFMA(ah, b0, ac0, 0, 0, 0); ac0 = MFMA(al, b0, ac0, 0, 0, 0);
                ac1 = MFMA(ah, b1, ac1, 0, 0, 0); ac1 = MFMA(al, b1, ac1, 0, 0, 0);
                ac2 = MFMA(ah, b2, ac2, 0, 0, 0); ac2 = MFMA(al, b2, ac2, 0, 0, 0);
            }
            const u32* h1H = a.h1HI + (size_t)t*HS;
            const u32* h1L = a.h1LO + (size_t)t*HS;
            int sh = (r16 & 1)*16;
            #pragma unroll
            for (int r = 0; r < 4; r++){
                int b = wv*16 + rg + r, j = jt*16 + r16;
                float gr = ac0[r] + a.bih1[j];
                float gz = ac1[r] + a.bih1[H + j];
                float gn = ac2[r] + a.bih1[2*H + j];
                float hr = cloadf(a.ghF + (size_t)b*H3 + j)       + a.bhh1[j];
                float hz = cloadf(a.ghF + (size_t)b*H3 + H + j)   + a.bhh1[H + j];
                float hn = cloadf(a.ghF + (size_t)b*H3 + 2*H + j) + a.bhh1[2*H + j];
                u32 uh = h1H[(size_t)b*512 + (j >> 1)];
                u32 ul = h1L[(size_t)b*512 + (j >> 1)];
                float h1v = bf2f((u16)(uh >> sh)) + bf2f((u16)(ul >> sh));
                float rr = sigm(gr + hr), zz = sigm(gz + hz);
                float nn = tanhf(gn + rr*hn);
                float hv = (1.f - zz)*nn + zz*h1v;
                a.h2all[((size_t)t*BB + b)*H + j] = f2bf(hv);
                u16 hib = f2bf(hv);
                u16 lob = f2bf(hv - bf2f(hib));
                u32 hip = (u32)__shfl_xor((int)(u32)hib, 1);
                u32 lop = (u32)__shfl_xor((int)(u32)lob, 1);
                if (!(r16 & 1)){
                    cstore(a.hsHI + (size_t)(t+1)*HS + (size_t)b*512 + (j >> 1), (u32)hib | (hip << 16));
                    cstore(a.hsLO + (size_t)(t+1)*HS + (size_t)b*512 + (j >> 1), (u32)lob | (lop << 16));
                }
            }
        }
        gbar(a.bar, &mygen, tid, bid);
    }
}

// ---------- fused final GEMM + row-max (excl tgt) + s_true ----------
__global__ __launch_bounds__(256) void k_final(const u16* __restrict__ logitf, const u16* __restrict__ Wf,
                                               const int* __restrict__ y, float* __restrict__ pmax,
                                               float* __restrict__ strue){
    __shared__ float red[128][2];
    int tid = threadIdx.x, w = tid >> 6, lane = tid & 63;
    int wm = w >> 1, wn = w & 1;
    int row0 = blockIdx.x*128 + wm*64;
    int col0 = blockIdx.y*128 + wn*64;
    int r16 = lane & 15, rg = (lane >> 4)*4;
    f32x4 acc[4][4] = {};
    for (int k0 = 0; k0 < 16; k0++){
        bf16x8 af[4], bfv[4];
        #pragma unroll
        for (int i = 0; i < 4; i++)
            af[i] = *(const bf16x8*)(logitf + (((size_t)((row0 >> 4) + i)*16 + k0) << 9) + lane*8);
        #pragma unroll
        for (int j = 0; j < 4; j++)
            bfv[j] = *(const bf16x8*)(Wf + (((size_t)((col0 >> 4) + j)*16 + k0) << 9) + lane*8);
        #pragma unroll
        for (int i = 0; i < 4; i++)
            #pragma unroll
            for (int j = 0; j < 4; j++)
                acc[i][j] = MFMA(af[i], bfv[j], acc[i][j], 0, 0, 0);
    }
    #pragma unroll
    for (int i = 0; i < 4; i++){
        #pragma unroll
        for (int r = 0; r < 4; r++){
            int row = row0 + i*16 + rg + r;
            int tgt = y[row + BB];
            float m = -1e30f;
            #pragma unroll
            for (int j = 0; j < 4; j++){
                float v = acc[i][j][r];
                int col = col0 + j*16 + r16;
                if (col == tgt){ strue[row] = v; v = -1e30f; }
                m = fmaxf(m, v);
            }
            m = fmaxf(m, __shfl_xor(m, 1));
            m = fmaxf(m, __shfl_xor(m, 2));
            m = fmaxf(m, __shfl_xor(m, 4));
            m = fmaxf(m, __shfl_xor(m, 8));
            if (r16 == 0) red[wm*64 + i*16 + rg + r][wn] = m;
        }
    }
    __syncthreads();
    if (tid < 128){
        float m = fmaxf(red[tid][0], red[tid][1]);
        pmax[(size_t)(blockIdx.x*128 + tid)*VCHUNKS + blockIdx.y] = m;
    }
}

__global__ __launch_bounds__(256) void k_loss(const float* __restrict__ pmax, const float* __restrict__ strue,
                                              const int* __restrict__ y, float* __restrict__ out){
    int R = blockIdx.x*256 + threadIdx.x;
    int lane = threadIdx.x & 63, wave = threadIdx.x >> 6;
    float l = 0.f;
    if (R < NROWS){
        int tgt = y[R + BB];
        if (tgt != 0){
            const float* pm = pmax + (size_t)R*VCHUNKS;
            float m = -1e30f;
            for (int i = 0; i < VCHUNKS; i++) m = fmaxf(m, pm[i]);
            l = fmaxf(FMARGIN - strue[R] + m, 0.f);
        }
    }
    #pragma unroll
    for (int off = 32; off; off >>= 1) l += __shfl_down(l, off);
    __shared__ float wsum[4];
    if (lane == 0) wsum[wave] = l;
    __syncthreads();
    if (threadIdx.x == 0) atomicAdd(out, wsum[0] + wsum[1] + wsum[2] + wsum[3]);
}

// ---------- launch ----------
extern "C" void kernel_launch(void* const* d_in, const int* in_sizes, int n_in,
                              void* d_out, int out_size, void* d_ws, size_t ws_size,
                              hipStream_t stream){
    const float* ctx    = (const float*)d_in[0];
    const float* mask   = (const float*)d_in[1];
    const int*   y      = (const int*)d_in[2];
    const float* emb_W  = (const float*)d_in[3];
    const float* W_init = (const float*)d_in[4];
    const float* b_init = (const float*)d_in[5];
    const float* W_ih0  = (const float*)d_in[6];
    const float* W_hh0  = (const float*)d_in[7];
    const float* b_ih0  = (const float*)d_in[8];
    const float* b_hh0  = (const float*)d_in[9];
    const float* W_c2c  = (const float*)d_in[10];
    const float* W_h2c  = (const float*)d_in[11];
    const float* v_att  = (const float*)d_in[12];
    const float* W_ih1  = (const float*)d_in[13];
    const float* W_hh1  = (const float*)d_in[14];
    const float* b_ih1  = (const float*)d_in[15];
    const float* b_hh1  = (const float*)d_in[16];
    const float* W_h2o  = (const float*)d_in[17];
    const float* b_h2o  = (const float*)d_in[18];
    const float* W_out  = (const float*)d_in[19];
    float* out = (float*)d_out;

    char* wsb = (char*)d_ws;
    size_t off = 0;
    auto alloc = [&](size_t bytes)->void*{
        void* p = (void*)(wsb + off);
        off = (off + bytes + 255) & ~(size_t)255;
        return p;
    };
    u16* Wih0f = (u16*)alloc((size_t)H3*DIN*2);
    u16* Whh0f = (u16*)alloc((size_t)H3*H*2);
    u16* Wih1f = (u16*)alloc((size_t)H3*H*2);
    u16* Whh1f = (u16*)alloc((size_t)H3*H*2);
    u16* Wh2cf = (u16*)alloc((size_t)H*H*2);
    u16* Wc2cf = (u16*)alloc((size_t)H*H*2);
    u16* Wh2of = (u16*)alloc((size_t)DIN*H*2);
    u16* Woutf = (u16*)alloc((size_t)VSZ*DIN*2);     // during recurrence: prF alias
    u16* ctxb  = (u16*)alloc((size_t)SS*BB*H*2);
    u16* ctxpb = (u16*)alloc((size_t)SS*BB*H*2);
    u16* embf  = (u16*)alloc((size_t)NROWS*DIN*2);
    u16* gi0b  = (u16*)alloc((size_t)NROWS*H3*2);    // reused after recurrence
    u16* h2allb= (u16*)alloc((size_t)NROWS*H*2);
    u32* hsHI  = (u32*)alloc((size_t)(TP+1)*HS*4);
    u32* hsLO  = (u32*)alloc((size_t)(TP+1)*HS*4);
    u32* h1HI  = (u32*)alloc((size_t)TP*HS*4);
    u32* h1LO  = (u32*)alloc((size_t)TP*HS*4);
    u32* ztHI  = (u32*)alloc((size_t)TP*HS*4);
    u32* ztLO  = (u32*)alloc((size_t)TP*HS*4);
    float* ghF = (float*)alloc((size_t)BB*H3*4);
    float* spar= (float*)alloc((size_t)TP*256*SS*4);   // 3 MB partial scores
    u32* bar   = (u32*)alloc(8192);
    u32* flg   = (u32*)alloc(32768);
    float* strue  = (float*)alloc(NROWS*4);
    float* msum   = (float*)alloc(BB*4);
    float* meanc  = (float*)alloc((size_t)BB*H*4);
    float* h0f    = (float*)alloc((size_t)BB*H*4);

    float* prF = (float*)Woutf;      // Woutf recomputed after recurrence

    float* logitf  = (float*)gi0b;
    u16*   logitfr = (u16*)(gi0b + (size_t)NROWS*DIN*2);
    float* pmax    = (float*)(gi0b + (size_t)NROWS*DIN*2 + (size_t)NROWS*DIN);

    hipMemsetAsync(d_out, 0, sizeof(float), stream);
    hipMemsetAsync(bar, 0, 8192, stream);
    hipMemsetAsync(flg, 0, 32768, stream);

    // ---- init ----
    hipLaunchKernelGGL(k_mask_sum, dim3(1), dim3(128), 0, stream, mask, msum);
    hipLaunchKernelGGL(k_mean_ctx, dim3(BB*H/256), dim3(256), 0, stream, ctx, msum, meanc);
    hipLaunchKernelGGL((k_gemm_nt<1>), dim3(H/64, BB/64), dim3(256), 0, stream,
                       meanc, W_init, b_init, h0f, BB, H, H);
    hipLaunchKernelGGL(k_pack_h0, dim3(HS/256), dim3(256), 0, stream, h0f, hsHI, hsLO);

    hipLaunchKernelGGL(k_f2bf_frag, dim3(H3*DIN/8/256), dim3(256), 0, stream, W_ih0, Wih0f, H3*DIN/8, DIN/8);
    hipLaunchKernelGGL(k_f2bf_frag, dim3(H3*H/8/256), dim3(256), 0, stream, W_hh0, Whh0f, H3*H/8, H/8);
    hipLaunchKernelGGL(k_f2bf_frag, dim3(H3*H/8/256), dim3(256), 0, stream, W_ih1, Wih1f, H3*H/8, H/8);
    hipLaunchKernelGGL(k_f2bf_frag, dim3(H3*H/8/256), dim3(256), 0, stream, W_hh1, Whh1f, H3*H/8, H/8);
    hipLaunchKernelGGL(k_f2bf_frag, dim3(H*H/8/256), dim3(256), 0, stream, W_h2c, Wh2cf, H*H/8, H/8);
    hipLaunchKernelGGL(k_f2bf_frag, dim3(H*H/8/256), dim3(256), 0, stream, W_c2c, Wc2cf, H*H/8, H/8);
    hipLaunchKernelGGL(k_f2bf_frag, dim3(DIN*H/8/256), dim3(256), 0, stream, W_h2o, Wh2of, DIN*H/8, H/8);
    hipLaunchKernelGGL(k_f32bf, dim3(SS*BB*H/4/256), dim3(256), 0, stream, ctx, ctxb, SS*BB*H/4);
    hipLaunchKernelGGL(k_emb_frag, dim3(NROWS/4), dim3(256), 0, stream, emb_W, y, embf);

    // ---- batched GEMMs ----
    hipLaunchKernelGGL((k_gemmf<1,0,u16>), dim3(H3/128, NROWS/128), dim3(256), 0, stream,
                       embf, Wih0f, b_ih0, gi0b, NROWS, H3, DIN);
    hipLaunchKernelGGL((k_gemmf<0,0,u16>), dim3(H/128, SS*BB/128), dim3(256), 0, stream,
                       ctxb, Wc2cf, (const float*)nullptr, ctxpb, SS*BB, H, H);

    // ---- persistent recurrence ----
    RJ rj;
    rj.gi0 = gi0b; rj.Whh0 = Whh0f; rj.Wh2c = Wh2cf; rj.Wih1 = Wih1f; rj.Whh1 = Whh1f;
    rj.ctxp = ctxpb;
    rj.bhh0 = b_hh0; rj.bih1 = b_ih1; rj.bhh1 = b_hh1; rj.vatt = v_att; rj.mask = mask; rj.ctxf = ctx;
    rj.hsHI = hsHI; rj.hsLO = hsLO; rj.h1HI = h1HI; rj.h1LO = h1LO; rj.ztHI = ztHI; rj.ztLO = ztLO;
    rj.prF = prF; rj.ghF = ghF; rj.spar = spar; rj.flg = flg;
    rj.h2all = h2allb; rj.bar = bar;
    void* kp[] = { (void*)&rj };
    hipLaunchCooperativeKernel((const void*)k_recur9, dim3(NBLK), dim3(512), kp, 0, stream);

    // ---- output head (Woutf recomputed now that prF alias is dead) ----
    hipLaunchKernelGGL(k_rownorm_frag, dim3(VSZ/4), dim3(256), 0, stream, W_out, Woutf, VSZ);
    hipLaunchKernelGGL((k_gemmf<0,1,float>), dim3(DIN/128, NROWS/128), dim3(256), 0, stream,
                       h2allb, Wh2of, b_h2o, logitf, NROWS, DIN, H);
    hipLaunchKernelGGL(k_rownorm_frag, dim3(NROWS/4), dim3(256), 0, stream, logitf, logitfr, NROWS);
    hipLaunchKernelGGL(k_final, dim3(NROWS/128, VSZ/128), dim3(256), 0, stream,
                       logitfr, Woutf, y, pmax, strue);
    hipLaunchKernelGGL(k_loss, dim3((NROWS + 255)/256), dim3(256), 0, stream, pmax, strue, y, out);
}